// Round 1
// baseline (256.995 us; speedup 1.0000x reference)
//
#include <hip/hip_runtime.h>

// Positional encoding off-grid: out[c, i] layout (256, num), row-major, fp32.
//   c in [0,128):   c=2k -> sin(y_i * f_k), c=2k+1 -> cos(y_i * f_k)
//   c in [128,256): c-128=2k -> sin(x_i * f_k), else cos(x_i * f_k)
//
// Write-BW bound: 268 MB out, ~2 MB in. Floor ~41-43 us @ 6.3-6.5 TB/s.
//
// Key structural choice (R1): loop over ALL 64 frequencies per thread with
// grid = (num/4/256, 2). All resident waves execute the same k at roughly the
// same time, so the chip-wide write footprint at any instant is a dense
// ~4 MB sliding window (rows 2k,2k+1 and 128+2k,128+2k+1) that sweeps the
// output in address order -- same DRAM page locality as the memset fills
// that hit 6.5 TB/s. The previous version (8 row-slices, full 2048-block
// residency) scattered 1 KB granules across the whole 268 MB buffer at once.

__global__ __launch_bounds__(256) void pe_offgrid_kernel(
    const float* __restrict__ YX,        // (2, num)
    const float* __restrict__ inv_freq,  // (64,)
    float* __restrict__ out,             // (256, num)
    int num)
{
    __shared__ float fshared[64];
    if (threadIdx.x < 64) fshared[threadIdx.x] = inv_freq[threadIdx.x];
    __syncthreads();

    const int i4 = blockIdx.x * blockDim.x + threadIdx.x;  // float4 chunk over i
    if (4 * i4 >= num) return;

    const bool isY = (blockIdx.y == 0);

    // coord values for the 4 consecutive i's this thread owns (read ONCE,
    // reused for all 64 frequencies)
    const float4 c4 = ((const float4*)(YX + (isY ? 0 : num)))[i4];

    float* base = out + (isY ? (size_t)0 : (size_t)128 * (size_t)num)
                      + (size_t)(4 * i4);
    const size_t rowStep = 2 * (size_t)num;   // advance 2 rows per k

#pragma unroll 8
    for (int k = 0; k < 64; ++k) {
        const float fr = fshared[k];

        float4 s, c;
        __sincosf(c4.x * fr, &s.x, &c.x);
        __sincosf(c4.y * fr, &s.y, &c.y);
        __sincosf(c4.z * fr, &s.z, &c.z);
        __sincosf(c4.w * fr, &s.w, &c.w);

        float* p = base + (size_t)k * rowStep;
        *(float4*)(p)        = s;   // sin row (c = 2k [+128])
        *(float4*)(p + num)  = c;   // cos row (c = 2k+1 [+128])
    }
}

extern "C" void kernel_launch(void* const* d_in, const int* in_sizes, int n_in,
                              void* d_out, int out_size, void* d_ws, size_t ws_size,
                              hipStream_t stream) {
    const float* YX       = (const float*)d_in[0];
    const float* inv_freq = (const float*)d_in[1];
    float* out            = (float*)d_out;

    const int num = in_sizes[0] / 2;          // 262144
    const int i4_total = (num + 3) / 4;       // 65536
    dim3 block(256);
    dim3 grid((i4_total + block.x - 1) / block.x, 2);  // 512 blocks, 2/CU
    pe_offgrid_kernel<<<grid, block, 0, stream>>>(YX, inv_freq, out, num);
}